// Round 11
// baseline (289.367 us; speedup 1.0000x reference)
//
#include <hip/hip_runtime.h>
#include <hip/hip_bf16.h>
#include <math.h>

#define IN_D 128
#define HID_D 128
#define OUT_D 64
#define CAP 64   // bucket capacity per node; Poisson(12) max over 50K nodes << 64

typedef __attribute__((ext_vector_type(8))) short bf16x8;
typedef __attribute__((ext_vector_type(4))) float f32x4;

__device__ __forceinline__ unsigned short f2bf(float f) {
    unsigned u = __float_as_uint(f);
    u += 0x7fffu + ((u >> 16) & 1u);   // RTNE
    return (unsigned short)(u >> 16);
}
__device__ __forceinline__ float bf2f(unsigned short h) {
    return __uint_as_float(((unsigned)h) << 16);
}

// ---- prep + XCD-partitioned edge fill (round-4/5 proven version, verbatim) ----
__global__ __launch_bounds__(256) void k_prep_fill(
        const int* __restrict__ src_idx, const int* __restrict__ dst_idx,
        int* __restrict__ cnt, unsigned short* __restrict__ elist,
        int E, int W, int range,
        const float* __restrict__ W1, const float* __restrict__ F1,
        const float* __restrict__ W2, const float* __restrict__ F2,
        const float* __restrict__ Wp,
        const float* __restrict__ X, unsigned short* __restrict__ fx, int nfv,
        unsigned short* __restrict__ wc1, unsigned short* __restrict__ wc2,
        unsigned short* __restrict__ wpb) {
    int e = blockIdx.x * 256 + threadIdx.x;
    if (e < nfv) {   // nfv = N*IN_D/16 vector-chunks of 16 floats
        const float4* xp = (const float4*)X + (size_t)e * 4;
        float4 v0 = xp[0], v1 = xp[1], v2 = xp[2], v3 = xp[3];
        uint4 o0, o1;
        o0.x = (unsigned)f2bf(v0.x) | ((unsigned)f2bf(v0.y) << 16);
        o0.y = (unsigned)f2bf(v0.z) | ((unsigned)f2bf(v0.w) << 16);
        o0.z = (unsigned)f2bf(v1.x) | ((unsigned)f2bf(v1.y) << 16);
        o0.w = (unsigned)f2bf(v1.z) | ((unsigned)f2bf(v1.w) << 16);
        o1.x = (unsigned)f2bf(v2.x) | ((unsigned)f2bf(v2.y) << 16);
        o1.y = (unsigned)f2bf(v2.z) | ((unsigned)f2bf(v2.w) << 16);
        o1.z = (unsigned)f2bf(v3.x) | ((unsigned)f2bf(v3.y) << 16);
        o1.w = (unsigned)f2bf(v3.z) | ((unsigned)f2bf(v3.w) << 16);
        ((uint4*)fx)[(size_t)e * 2]     = o0;
        ((uint4*)fx)[(size_t)e * 2 + 1] = o1;
    }
    const int NW = HID_D * IN_D;          // 16384
    const int NC = 3 * NW;                // 49152
    const int NP = OUT_D * HID_D;         // 8192
    int i = e;
    if (i < NC) {
        wc1[i] = f2bf(i < NW ? W1[i] : F1[i - NW]);
    } else if (i < 2 * NC) {
        int j = i - NC;
        wc2[j] = f2bf(j < NW ? W2[j] : F2[j - NW]);
    } else if (i < 2 * NC + NP) {
        int j = i - 2 * NC;
        wpb[j] = f2bf(Wp[j]);
    }

    // ---- edge fill: group g scans edge window of sub-block, keeps its range
    const int g = blockIdx.x & 7;          // intended XCD id (bid%8 round-robin)
    const int sub = blockIdx.x >> 3;       // 0..255
    const int lo = g * range;
    const int base = sub * W;
    int end = base + W;
    if (end > E) end = E;
    for (int ed = base + threadIdx.x; ed < end; ed += 256) {
        int d = dst_idx[ed];
        int s = src_idx[ed];               // coalesced; ~88% of lines needed anyway
        if ((unsigned)(d - lo) < (unsigned)range) {
            int pos = atomicAdd(&cnt[d], 1);
            elist[(size_t)d * CAP + pos] = (unsigned short)s;
        }
    }
}

// ---- fused GEMM + FiLM (round-5 proven config, verbatim) ----
__global__ __launch_bounds__(256, 2) void k_msg(const unsigned short* __restrict__ X,
                                                const unsigned short* __restrict__ Wc,
                                                unsigned short* __restrict__ Msg,
                                                int n, int nchunks) {
    const int wave = threadIdx.x >> 6;
    const int lane = threadIdx.x & 63;
    const int lr = lane & 15;
    const int quad = lane >> 4;
    const int t0 = wave * 2;
    const int tidx[6] = {t0, t0 + 1, t0 + 8, t0 + 9, t0 + 16, t0 + 17};

    bf16x8 b[6][4];
    #pragma unroll
    for (int u = 0; u < 6; u++)
        #pragma unroll
        for (int s = 0; s < 4; s++)
            b[u][s] = *(const bf16x8*)(Wc + (size_t)(16 * tidx[u] + lr) * IN_D + quad * 8 + 32 * s);

    for (int c = blockIdx.x; c < nchunks; c += gridDim.x) {
        const int row0 = c << 4;   // 16 rows per chunk

        int r = row0 + lr;
        if (r > n - 1) r = n - 1;
        const unsigned short* xp = X + (size_t)r * IN_D + quad * 8;
        bf16x8 a[4];
        #pragma unroll
        for (int s = 0; s < 4; s++) a[s] = *(const bf16x8*)(xp + 32 * s);

        f32x4 acc[6];
        #pragma unroll
        for (int u = 0; u < 6; u++) acc[u] = (f32x4){0.f, 0.f, 0.f, 0.f};

        #pragma unroll
        for (int s = 0; s < 4; s++)
            #pragma unroll
            for (int u = 0; u < 6; u++)
                acc[u] = __builtin_amdgcn_mfma_f32_16x16x32_bf16(a[s], b[u][s], acc[u], 0, 0, 0);

        #pragma unroll
        for (int u = 0; u < 2; u++) {
            #pragma unroll
            for (int rr = 0; rr < 4; rr++) {
                int row = row0 + quad * 4 + rr;
                if (row < n) {
                    float v = acc[2 + u][rr] * acc[u][rr] + acc[4 + u][rr];
                    v = v > 0.f ? v : 0.f;
                    Msg[(size_t)row * HID_D + 16 * (t0 + u) + lr] = f2bf(v);
                }
            }
        }
    }
}

// ---- bucket aggregate + fused LayerNorm (round-5 proven loop, verbatim) ----
__global__ __launch_bounds__(256) void k_agg_ln(const unsigned short* __restrict__ Msg,
                                                const unsigned short* __restrict__ elist,
                                                const int* __restrict__ cnt,
                                                const float* __restrict__ gamma,
                                                const float* __restrict__ beta,
                                                unsigned short* __restrict__ Hout, int n) {
    int node = blockIdx.x * 4 + (threadIdx.x >> 6);
    int lane = threadIdx.x & 63;
    int g = lane >> 4;        // row-group 0..3
    int l16 = lane & 15;      // dims [l16*8, l16*8+8)
    if (node >= n) return;    // wave-uniform
    const unsigned short* seg = elist + (size_t)node * CAP;
    int deg = cnt[node];
    int myidx = seg[lane];    // one coalesced 128B load per wave
    float a0 = 0.f, a1 = 0.f, a2 = 0.f, a3 = 0.f;
    float a4 = 0.f, a5 = 0.f, a6 = 0.f, a7 = 0.f;

#define ACC8(v) { a0 += bf2f((unsigned short)((v).x & 0xffffu)); \
                  a1 += bf2f((unsigned short)((v).x >> 16));     \
                  a2 += bf2f((unsigned short)((v).y & 0xffffu)); \
                  a3 += bf2f((unsigned short)((v).y >> 16));     \
                  a4 += bf2f((unsigned short)((v).z & 0xffffu)); \
                  a5 += bf2f((unsigned short)((v).z >> 16));     \
                  a6 += bf2f((unsigned short)((v).w & 0xffffu)); \
                  a7 += bf2f((unsigned short)((v).w >> 16)); }

    int i = 0;
    for (; i + 8 <= deg; i += 8) {            // uniform condition
        int iA = __shfl(myidx, i + g);         // sources < deg, all lanes active
        int iB = __shfl(myidx, i + 4 + g);
        uint4 vA = *(const uint4*)(Msg + (size_t)iA * HID_D + l16 * 8);
        uint4 vB = *(const uint4*)(Msg + (size_t)iB * HID_D + l16 * 8);
        ACC8(vA);
        ACC8(vB);
    }
    if (i + 4 <= deg) {                        // uniform
        int iA = __shfl(myidx, i + g);
        uint4 vA = *(const uint4*)(Msg + (size_t)iA * HID_D + l16 * 8);
        ACC8(vA);
        i += 4;
    }
    int rem = deg - i;                         // uniform, 0..3
    if (rem) {                                 // uniform
        int iA = __shfl(myidx, i + (g < rem ? g : 0));  // source < deg
        if (g < rem) {                         // divergent load only, no shfl inside
            uint4 vA = *(const uint4*)(Msg + (size_t)iA * HID_D + l16 * 8);
            ACC8(vA);
        }
    }
#undef ACC8

    a0 += __shfl_xor(a0, 16); a1 += __shfl_xor(a1, 16);
    a2 += __shfl_xor(a2, 16); a3 += __shfl_xor(a3, 16);
    a4 += __shfl_xor(a4, 16); a5 += __shfl_xor(a5, 16);
    a6 += __shfl_xor(a6, 16); a7 += __shfl_xor(a7, 16);
    a0 += __shfl_xor(a0, 32); a1 += __shfl_xor(a1, 32);
    a2 += __shfl_xor(a2, 32); a3 += __shfl_xor(a3, 32);
    a4 += __shfl_xor(a4, 32); a5 += __shfl_xor(a5, 32);
    a6 += __shfl_xor(a6, 32); a7 += __shfl_xor(a7, 32);

    float s  = a0 + a1 + a2 + a3 + a4 + a5 + a6 + a7;
    float sq = a0 * a0 + a1 * a1 + a2 * a2 + a3 * a3
             + a4 * a4 + a5 * a5 + a6 * a6 + a7 * a7;
    #pragma unroll
    for (int d = 8; d; d >>= 1) {
        s += __shfl_xor(s, d);
        sq += __shfl_xor(sq, d);
    }
    float mu = s * (1.f / 128.f);
    float var = sq * (1.f / 128.f) - mu * mu;
    float rs = rsqrtf(var + 1e-5f);

    if (g == 0) {
        float4 g0 = ((const float4*)gamma)[l16 * 2];
        float4 g1 = ((const float4*)gamma)[l16 * 2 + 1];
        float4 b0 = ((const float4*)beta)[l16 * 2];
        float4 b1 = ((const float4*)beta)[l16 * 2 + 1];
        float y0 = (a0 - mu) * rs * g0.x + b0.x;
        float y1 = (a1 - mu) * rs * g0.y + b0.y;
        float y2 = (a2 - mu) * rs * g0.z + b0.z;
        float y3 = (a3 - mu) * rs * g0.w + b0.w;
        float y4 = (a4 - mu) * rs * g1.x + b1.x;
        float y5 = (a5 - mu) * rs * g1.y + b1.y;
        float y6 = (a6 - mu) * rs * g1.z + b1.z;
        float y7 = (a7 - mu) * rs * g1.w + b1.w;
        uint4 o;
        o.x = (unsigned)f2bf(y0) | ((unsigned)f2bf(y1) << 16);
        o.y = (unsigned)f2bf(y2) | ((unsigned)f2bf(y3) << 16);
        o.z = (unsigned)f2bf(y4) | ((unsigned)f2bf(y5) << 16);
        o.w = (unsigned)f2bf(y6) | ((unsigned)f2bf(y7) << 16);
        *(uint4*)(Hout + (size_t)node * HID_D + l16 * 8) = o;
    }
}

// ---- agg2 + LayerNorm + fused projection + sigmoid ----
// Same gather/LN as k_agg_ln; then in-wave proj: every lane holds the full
// 128-dim row after the xor reductions, lane o owns output channel o.
// The PROJ math PASSED on HW in round 8 but at VGPR_Count=28 -> scratch spill
// (112 us). Fix: separate non-templated kernel + launch_bounds(256,2), which
// grants up to 256 VGPR and stops the occupancy heuristic from strangling it.
__global__ __launch_bounds__(256, 2) void k_agg_ln_proj(
        const unsigned short* __restrict__ Msg,
        const unsigned short* __restrict__ elist,
        const int* __restrict__ cnt,
        const float* __restrict__ gamma,
        const float* __restrict__ beta,
        int n,
        const unsigned short* __restrict__ Wpb,
        const float* __restrict__ bp,
        float* __restrict__ out) {
    int node = blockIdx.x * 4 + (threadIdx.x >> 6);
    int lane = threadIdx.x & 63;
    int g = lane >> 4;
    int l16 = lane & 15;
    if (node >= n) return;    // wave-uniform
    const unsigned short* seg = elist + (size_t)node * CAP;
    int deg = cnt[node];
    int myidx = seg[lane];
    float a0 = 0.f, a1 = 0.f, a2 = 0.f, a3 = 0.f;
    float a4 = 0.f, a5 = 0.f, a6 = 0.f, a7 = 0.f;

#define ACC8(v) { a0 += bf2f((unsigned short)((v).x & 0xffffu)); \
                  a1 += bf2f((unsigned short)((v).x >> 16));     \
                  a2 += bf2f((unsigned short)((v).y & 0xffffu)); \
                  a3 += bf2f((unsigned short)((v).y >> 16));     \
                  a4 += bf2f((unsigned short)((v).z & 0xffffu)); \
                  a5 += bf2f((unsigned short)((v).z >> 16));     \
                  a6 += bf2f((unsigned short)((v).w & 0xffffu)); \
                  a7 += bf2f((unsigned short)((v).w >> 16)); }

    int i = 0;
    for (; i + 8 <= deg; i += 8) {
        int iA = __shfl(myidx, i + g);
        int iB = __shfl(myidx, i + 4 + g);
        uint4 vA = *(const uint4*)(Msg + (size_t)iA * HID_D + l16 * 8);
        uint4 vB = *(const uint4*)(Msg + (size_t)iB * HID_D + l16 * 8);
        ACC8(vA);
        ACC8(vB);
    }
    if (i + 4 <= deg) {
        int iA = __shfl(myidx, i + g);
        uint4 vA = *(const uint4*)(Msg + (size_t)iA * HID_D + l16 * 8);
        ACC8(vA);
        i += 4;
    }
    int rem = deg - i;
    if (rem) {
        int iA = __shfl(myidx, i + (g < rem ? g : 0));
        if (g < rem) {
            uint4 vA = *(const uint4*)(Msg + (size_t)iA * HID_D + l16 * 8);
            ACC8(vA);
        }
    }
#undef ACC8

    a0 += __shfl_xor(a0, 16); a1 += __shfl_xor(a1, 16);
    a2 += __shfl_xor(a2, 16); a3 += __shfl_xor(a3, 16);
    a4 += __shfl_xor(a4, 16); a5 += __shfl_xor(a5, 16);
    a6 += __shfl_xor(a6, 16); a7 += __shfl_xor(a7, 16);
    a0 += __shfl_xor(a0, 32); a1 += __shfl_xor(a1, 32);
    a2 += __shfl_xor(a2, 32); a3 += __shfl_xor(a3, 32);
    a4 += __shfl_xor(a4, 32); a5 += __shfl_xor(a5, 32);
    a6 += __shfl_xor(a6, 32); a7 += __shfl_xor(a7, 32);

    float s  = a0 + a1 + a2 + a3 + a4 + a5 + a6 + a7;
    float sq = a0 * a0 + a1 * a1 + a2 * a2 + a3 * a3
             + a4 * a4 + a5 * a5 + a6 * a6 + a7 * a7;
    #pragma unroll
    for (int d = 8; d; d >>= 1) {
        s += __shfl_xor(s, d);
        sq += __shfl_xor(sq, d);
    }
    float mu = s * (1.f / 128.f);
    float var = sq * (1.f / 128.f) - mu * mu;
    float rs = rsqrtf(var + 1e-5f);

    // y in ALL lanes (identical across the 4 g-replicas)
    float4 gg0 = ((const float4*)gamma)[l16 * 2];
    float4 gg1 = ((const float4*)gamma)[l16 * 2 + 1];
    float4 bb0 = ((const float4*)beta)[l16 * 2];
    float4 bb1 = ((const float4*)beta)[l16 * 2 + 1];
    float y0 = (a0 - mu) * rs * gg0.x + bb0.x;
    float y1 = (a1 - mu) * rs * gg0.y + bb0.y;
    float y2 = (a2 - mu) * rs * gg0.z + bb0.z;
    float y3 = (a3 - mu) * rs * gg0.w + bb0.w;
    float y4 = (a4 - mu) * rs * gg1.x + bb1.x;
    float y5 = (a5 - mu) * rs * gg1.y + bb1.y;
    float y6 = (a6 - mu) * rs * gg1.z + bb1.z;
    float y7 = (a7 - mu) * rs * gg1.w + bb1.w;

    float acc = bp[lane];                  // lane o = output channel o
    #pragma unroll
    for (int j = 0; j < 16; j++) {         // broadcast dims 8j..8j+7 from lane j
        float h0 = __shfl(y0, j);
        float h1 = __shfl(y1, j);
        float h2 = __shfl(y2, j);
        float h3 = __shfl(y3, j);
        float h4 = __shfl(y4, j);
        float h5 = __shfl(y5, j);
        float h6 = __shfl(y6, j);
        float h7 = __shfl(y7, j);
        bf16x8 w = *(const bf16x8*)(Wpb + (size_t)lane * HID_D + j * 8);
        acc += h0 * bf2f((unsigned short)w[0]);
        acc += h1 * bf2f((unsigned short)w[1]);
        acc += h2 * bf2f((unsigned short)w[2]);
        acc += h3 * bf2f((unsigned short)w[3]);
        acc += h4 * bf2f((unsigned short)w[4]);
        acc += h5 * bf2f((unsigned short)w[5]);
        acc += h6 * bf2f((unsigned short)w[6]);
        acc += h7 * bf2f((unsigned short)w[7]);
    }
    out[(size_t)node * OUT_D + lane] = 1.f / (1.f + __expf(-acc));
}

extern "C" void kernel_launch(void* const* d_in, const int* in_sizes, int n_in,
                              void* d_out, int out_size, void* d_ws, size_t ws_size,
                              hipStream_t stream) {
    const float* features = (const float*)d_in[0];
    const int* src = (const int*)d_in[1];
    const int* dst = (const int*)d_in[2];
    const float* W1 = (const float*)d_in[3];
    const float* F1 = (const float*)d_in[4];
    const float* g1 = (const float*)d_in[5];
    const float* b1 = (const float*)d_in[6];
    const float* W2 = (const float*)d_in[7];
    const float* F2 = (const float*)d_in[8];
    const float* g2 = (const float*)d_in[9];
    const float* b2 = (const float*)d_in[10];
    const float* Wp = (const float*)d_in[11];
    const float* bp = (const float*)d_in[12];

    const int N = in_sizes[0] / IN_D;   // 50000
    const int E = in_sizes[1];          // 600000
    float* out = (float*)d_out;

    char* p = (char*)d_ws;
    auto alloc = [&](size_t b) -> char* {
        char* r = p;
        p += (b + 255) & ~(size_t)255;
        return r;
    };
    unsigned short* buf0 = (unsigned short*)alloc((size_t)N * HID_D * 2);
    unsigned short* buf1 = (unsigned short*)alloc((size_t)N * HID_D * 2);
    unsigned short* fx   = (unsigned short*)alloc((size_t)N * IN_D * 2);
    unsigned short* wc1  = (unsigned short*)alloc((size_t)3 * HID_D * IN_D * 2);
    unsigned short* wc2  = (unsigned short*)alloc((size_t)3 * HID_D * HID_D * 2);
    unsigned short* wpb  = (unsigned short*)alloc((size_t)OUT_D * HID_D * 2);
    int* cnt    = (int*)alloc((size_t)N * 4);
    unsigned short* elist = (unsigned short*)alloc((size_t)N * CAP * 2);  // 6.4 MB

    const int mc = (N + 15) / 16;         // 3125 chunks (16 rows)
    const int mg = 512;                   // 2 blocks/CU, persistent grid-stride
    const int ab = (N + 3) / 4;           // 12500
    const int nfv = (N * IN_D) / 16;      // 400000
    const int fb = 2048;                  // 8 groups x 256 sub-blocks
    const int W = (E + 255) / 256;        // 2344 edges per sub-block window
    const int range = (N + 7) / 8;        // 6250 nodes per XCD group

    // cnt zeroed before the fill's atomics (separate dispatch: no race)
    hipMemsetAsync(cnt, 0, (size_t)N * 4, stream);
    // prep (weights+features->bf16) + XCD-partitioned edge fill
    k_prep_fill<<<fb, 256, 0, stream>>>(src, dst, cnt, elist, E, W, range,
                                        W1, F1, W2, F2, Wp,
                                        features, fx, nfv, wc1, wc2, wpb);

    // layer 1
    k_msg<<<mg, 256, 0, stream>>>(fx, wc1, buf1, N, mc);
    k_agg_ln<<<ab, 256, 0, stream>>>(buf1, elist, cnt, g1, b1, buf0, N);
    // layer 2 (+ fused projection & sigmoid)
    k_msg<<<mg, 256, 0, stream>>>(buf0, wc2, buf1, N, mc);
    k_agg_ln_proj<<<ab, 256, 0, stream>>>(buf1, elist, cnt, g2, b2, N,
                                          wpb, bp, out);
}

// Round 12
// 232.818 us; speedup vs baseline: 1.2429x; 1.2429x over previous
//
#include <hip/hip_runtime.h>
#include <hip/hip_bf16.h>
#include <math.h>

#define IN_D 128
#define HID_D 128
#define OUT_D 64
#define CAP 64   // bucket capacity per node; Poisson(12) max over 50K nodes << 64

typedef __attribute__((ext_vector_type(8))) short bf16x8;
typedef __attribute__((ext_vector_type(4))) float f32x4;

__device__ __forceinline__ unsigned short f2bf(float f) {
    unsigned u = __float_as_uint(f);
    u += 0x7fffu + ((u >> 16) & 1u);   // RTNE
    return (unsigned short)(u >> 16);
}
__device__ __forceinline__ float bf2f(unsigned short h) {
    return __uint_as_float(((unsigned)h) << 16);
}

// ---- prep + XCD-partitioned edge fill (round-4/5 proven version, verbatim) ----
__global__ __launch_bounds__(256) void k_prep_fill(
        const int* __restrict__ src_idx, const int* __restrict__ dst_idx,
        int* __restrict__ cnt, unsigned short* __restrict__ elist,
        int E, int W, int range,
        const float* __restrict__ W1, const float* __restrict__ F1,
        const float* __restrict__ W2, const float* __restrict__ F2,
        const float* __restrict__ Wp,
        const float* __restrict__ X, unsigned short* __restrict__ fx, int nfv,
        unsigned short* __restrict__ wc1, unsigned short* __restrict__ wc2,
        unsigned short* __restrict__ wpb) {
    int e = blockIdx.x * 256 + threadIdx.x;
    if (e < nfv) {   // nfv = N*IN_D/16 vector-chunks of 16 floats
        const float4* xp = (const float4*)X + (size_t)e * 4;
        float4 v0 = xp[0], v1 = xp[1], v2 = xp[2], v3 = xp[3];
        uint4 o0, o1;
        o0.x = (unsigned)f2bf(v0.x) | ((unsigned)f2bf(v0.y) << 16);
        o0.y = (unsigned)f2bf(v0.z) | ((unsigned)f2bf(v0.w) << 16);
        o0.z = (unsigned)f2bf(v1.x) | ((unsigned)f2bf(v1.y) << 16);
        o0.w = (unsigned)f2bf(v1.z) | ((unsigned)f2bf(v1.w) << 16);
        o1.x = (unsigned)f2bf(v2.x) | ((unsigned)f2bf(v2.y) << 16);
        o1.y = (unsigned)f2bf(v2.z) | ((unsigned)f2bf(v2.w) << 16);
        o1.z = (unsigned)f2bf(v3.x) | ((unsigned)f2bf(v3.y) << 16);
        o1.w = (unsigned)f2bf(v3.z) | ((unsigned)f2bf(v3.w) << 16);
        ((uint4*)fx)[(size_t)e * 2]     = o0;
        ((uint4*)fx)[(size_t)e * 2 + 1] = o1;
    }
    const int NW = HID_D * IN_D;          // 16384
    const int NC = 3 * NW;                // 49152
    const int NP = OUT_D * HID_D;         // 8192
    int i = e;
    if (i < NC) {
        wc1[i] = f2bf(i < NW ? W1[i] : F1[i - NW]);
    } else if (i < 2 * NC) {
        int j = i - NC;
        wc2[j] = f2bf(j < NW ? W2[j] : F2[j - NW]);
    } else if (i < 2 * NC + NP) {
        int j = i - 2 * NC;
        wpb[j] = f2bf(Wp[j]);
    }

    // ---- edge fill: group g scans edge window of sub-block, keeps its range
    const int g = blockIdx.x & 7;          // intended XCD id (bid%8 round-robin)
    const int sub = blockIdx.x >> 3;       // 0..255
    const int lo = g * range;
    const int base = sub * W;
    int end = base + W;
    if (end > E) end = E;
    for (int ed = base + threadIdx.x; ed < end; ed += 256) {
        int d = dst_idx[ed];
        int s = src_idx[ed];               // coalesced; ~88% of lines needed anyway
        if ((unsigned)(d - lo) < (unsigned)range) {
            int pos = atomicAdd(&cnt[d], 1);
            elist[(size_t)d * CAP + pos] = (unsigned short)s;
        }
    }
}

// ---- fused GEMM + FiLM: 8 waves/block (512 thr), 3 tiles/wave ----
// B-residency fix: round-3 PMC showed VGPR_Count=72 while the 4-wave body
// wanted b[6][4]=96 regs -> compiler reloaded B from L2 every chunk (~300MB
// L2 traffic/kernel + lgkmcnt stalls). 3 tiles/wave = b[3][4]=48 regs +
// acc 12 + a 16 + addr ~= 90 < 128 cap at launch_bounds(512,4) -> truly
// register-resident B, and 2x occupancy (16 waves/CU vs 8).
// Wave w owns output cols [16w,16w+16): tiles {w, 8+w, 16+w} of Wc
// (= W rows 16w.., gamma rows 128+16w.., beta rows 256+16w..).
__global__ __launch_bounds__(512, 4) void k_msg(const unsigned short* __restrict__ X,
                                                const unsigned short* __restrict__ Wc,
                                                unsigned short* __restrict__ Msg,
                                                int n, int nchunks) {
    const int wave = threadIdx.x >> 6;   // 0..7
    const int lane = threadIdx.x & 63;
    const int lr = lane & 15;
    const int quad = lane >> 4;

    // B fragments: 12 x 16B per lane, loaded once, register-resident
    bf16x8 b[3][4];
    #pragma unroll
    for (int u = 0; u < 3; u++)
        #pragma unroll
        for (int s = 0; s < 4; s++)
            b[u][s] = *(const bf16x8*)(Wc + (size_t)(16 * (u * 8 + wave) + lr) * IN_D + quad * 8 + 32 * s);

    for (int c = blockIdx.x; c < nchunks; c += gridDim.x) {
        const int row0 = c << 4;   // 16 rows per chunk

        int r = row0 + lr;
        if (r > n - 1) r = n - 1;
        const unsigned short* xp = X + (size_t)r * IN_D + quad * 8;
        bf16x8 a[4];
        #pragma unroll
        for (int s = 0; s < 4; s++) a[s] = *(const bf16x8*)(xp + 32 * s);

        f32x4 acc[3];
        #pragma unroll
        for (int u = 0; u < 3; u++) acc[u] = (f32x4){0.f, 0.f, 0.f, 0.f};

        #pragma unroll
        for (int s = 0; s < 4; s++)
            #pragma unroll
            for (int u = 0; u < 3; u++)
                acc[u] = __builtin_amdgcn_mfma_f32_16x16x32_bf16(a[s], b[u][s], acc[u], 0, 0, 0);

        // FiLM: m=acc[0], gamma=acc[1], beta=acc[2]; identical C-slots.
        #pragma unroll
        for (int rr = 0; rr < 4; rr++) {
            int row = row0 + quad * 4 + rr;
            if (row < n) {
                float v = acc[1][rr] * acc[0][rr] + acc[2][rr];
                v = v > 0.f ? v : 0.f;
                Msg[(size_t)row * HID_D + 16 * wave + lr] = f2bf(v);
            }
        }
    }
}

// ---- bucket aggregate + fused LayerNorm (round-5 proven loop, verbatim) ----
__global__ __launch_bounds__(256) void k_agg_ln(const unsigned short* __restrict__ Msg,
                                                const unsigned short* __restrict__ elist,
                                                const int* __restrict__ cnt,
                                                const float* __restrict__ gamma,
                                                const float* __restrict__ beta,
                                                unsigned short* __restrict__ Hout, int n) {
    int node = blockIdx.x * 4 + (threadIdx.x >> 6);
    int lane = threadIdx.x & 63;
    int g = lane >> 4;        // row-group 0..3
    int l16 = lane & 15;      // dims [l16*8, l16*8+8)
    if (node >= n) return;    // wave-uniform
    const unsigned short* seg = elist + (size_t)node * CAP;
    int deg = cnt[node];
    int myidx = seg[lane];    // one coalesced 128B load per wave
    float a0 = 0.f, a1 = 0.f, a2 = 0.f, a3 = 0.f;
    float a4 = 0.f, a5 = 0.f, a6 = 0.f, a7 = 0.f;

#define ACC8(v) { a0 += bf2f((unsigned short)((v).x & 0xffffu)); \
                  a1 += bf2f((unsigned short)((v).x >> 16));     \
                  a2 += bf2f((unsigned short)((v).y & 0xffffu)); \
                  a3 += bf2f((unsigned short)((v).y >> 16));     \
                  a4 += bf2f((unsigned short)((v).z & 0xffffu)); \
                  a5 += bf2f((unsigned short)((v).z >> 16));     \
                  a6 += bf2f((unsigned short)((v).w & 0xffffu)); \
                  a7 += bf2f((unsigned short)((v).w >> 16)); }

    int i = 0;
    for (; i + 8 <= deg; i += 8) {            // uniform condition
        int iA = __shfl(myidx, i + g);         // sources < deg, all lanes active
        int iB = __shfl(myidx, i + 4 + g);
        uint4 vA = *(const uint4*)(Msg + (size_t)iA * HID_D + l16 * 8);
        uint4 vB = *(const uint4*)(Msg + (size_t)iB * HID_D + l16 * 8);
        ACC8(vA);
        ACC8(vB);
    }
    if (i + 4 <= deg) {                        // uniform
        int iA = __shfl(myidx, i + g);
        uint4 vA = *(const uint4*)(Msg + (size_t)iA * HID_D + l16 * 8);
        ACC8(vA);
        i += 4;
    }
    int rem = deg - i;                         // uniform, 0..3
    if (rem) {                                 // uniform
        int iA = __shfl(myidx, i + (g < rem ? g : 0));  // source < deg
        if (g < rem) {                         // divergent load only, no shfl inside
            uint4 vA = *(const uint4*)(Msg + (size_t)iA * HID_D + l16 * 8);
            ACC8(vA);
        }
    }
#undef ACC8

    a0 += __shfl_xor(a0, 16); a1 += __shfl_xor(a1, 16);
    a2 += __shfl_xor(a2, 16); a3 += __shfl_xor(a3, 16);
    a4 += __shfl_xor(a4, 16); a5 += __shfl_xor(a5, 16);
    a6 += __shfl_xor(a6, 16); a7 += __shfl_xor(a7, 16);
    a0 += __shfl_xor(a0, 32); a1 += __shfl_xor(a1, 32);
    a2 += __shfl_xor(a2, 32); a3 += __shfl_xor(a3, 32);
    a4 += __shfl_xor(a4, 32); a5 += __shfl_xor(a5, 32);
    a6 += __shfl_xor(a6, 32); a7 += __shfl_xor(a7, 32);

    float s  = a0 + a1 + a2 + a3 + a4 + a5 + a6 + a7;
    float sq = a0 * a0 + a1 * a1 + a2 * a2 + a3 * a3
             + a4 * a4 + a5 * a5 + a6 * a6 + a7 * a7;
    #pragma unroll
    for (int d = 8; d; d >>= 1) {
        s += __shfl_xor(s, d);
        sq += __shfl_xor(sq, d);
    }
    float mu = s * (1.f / 128.f);
    float var = sq * (1.f / 128.f) - mu * mu;
    float rs = rsqrtf(var + 1e-5f);

    if (g == 0) {
        float4 g0 = ((const float4*)gamma)[l16 * 2];
        float4 g1 = ((const float4*)gamma)[l16 * 2 + 1];
        float4 b0 = ((const float4*)beta)[l16 * 2];
        float4 b1 = ((const float4*)beta)[l16 * 2 + 1];
        float y0 = (a0 - mu) * rs * g0.x + b0.x;
        float y1 = (a1 - mu) * rs * g0.y + b0.y;
        float y2 = (a2 - mu) * rs * g0.z + b0.z;
        float y3 = (a3 - mu) * rs * g0.w + b0.w;
        float y4 = (a4 - mu) * rs * g1.x + b1.x;
        float y5 = (a5 - mu) * rs * g1.y + b1.y;
        float y6 = (a6 - mu) * rs * g1.z + b1.z;
        float y7 = (a7 - mu) * rs * g1.w + b1.w;
        uint4 o;
        o.x = (unsigned)f2bf(y0) | ((unsigned)f2bf(y1) << 16);
        o.y = (unsigned)f2bf(y2) | ((unsigned)f2bf(y3) << 16);
        o.z = (unsigned)f2bf(y4) | ((unsigned)f2bf(y5) << 16);
        o.w = (unsigned)f2bf(y6) | ((unsigned)f2bf(y7) << 16);
        *(uint4*)(Hout + (size_t)node * HID_D + l16 * 8) = o;
    }
}

// ---- projection: out = sigmoid(h @ Wp^T + bp), 64 rows/block (round-5) ----
__global__ __launch_bounds__(256) void k_proj(const unsigned short* __restrict__ H,
                                              const unsigned short* __restrict__ Wpb,
                                              const float* __restrict__ bp,
                                              float* __restrict__ out, int n) {
    const int row0 = blockIdx.x << 6;
    const int wave = threadIdx.x >> 6;
    const int lane = threadIdx.x & 63;
    const int lr = lane & 15;
    const int quad = lane >> 4;

    f32x4 acc[4];
    #pragma unroll
    for (int rt = 0; rt < 4; rt++) acc[rt] = (f32x4){0.f, 0.f, 0.f, 0.f};

    #pragma unroll
    for (int s = 0; s < 4; s++) {
        bf16x8 bv = *(const bf16x8*)(Wpb + (size_t)(16 * wave + lr) * HID_D + quad * 8 + 32 * s);
        #pragma unroll
        for (int rt = 0; rt < 4; rt++) {
            int r = row0 + rt * 16 + lr;
            if (r > n - 1) r = n - 1;
            bf16x8 av = *(const bf16x8*)(H + (size_t)r * HID_D + quad * 8 + 32 * s);
            acc[rt] = __builtin_amdgcn_mfma_f32_16x16x32_bf16(av, bv, acc[rt], 0, 0, 0);
        }
    }
    float bias = bp[16 * wave + lr];
    #pragma unroll
    for (int rt = 0; rt < 4; rt++) {
        #pragma unroll
        for (int r = 0; r < 4; r++) {
            int row = row0 + rt * 16 + quad * 4 + r;
            if (row < n) {
                float z = acc[rt][r] + bias;
                out[(size_t)row * OUT_D + 16 * wave + lr] = 1.f / (1.f + __expf(-z));
            }
        }
    }
}

extern "C" void kernel_launch(void* const* d_in, const int* in_sizes, int n_in,
                              void* d_out, int out_size, void* d_ws, size_t ws_size,
                              hipStream_t stream) {
    const float* features = (const float*)d_in[0];
    const int* src = (const int*)d_in[1];
    const int* dst = (const int*)d_in[2];
    const float* W1 = (const float*)d_in[3];
    const float* F1 = (const float*)d_in[4];
    const float* g1 = (const float*)d_in[5];
    const float* b1 = (const float*)d_in[6];
    const float* W2 = (const float*)d_in[7];
    const float* F2 = (const float*)d_in[8];
    const float* g2 = (const float*)d_in[9];
    const float* b2 = (const float*)d_in[10];
    const float* Wp = (const float*)d_in[11];
    const float* bp = (const float*)d_in[12];

    const int N = in_sizes[0] / IN_D;   // 50000
    const int E = in_sizes[1];          // 600000
    float* out = (float*)d_out;

    char* p = (char*)d_ws;
    auto alloc = [&](size_t b) -> char* {
        char* r = p;
        p += (b + 255) & ~(size_t)255;
        return r;
    };
    unsigned short* buf0 = (unsigned short*)alloc((size_t)N * HID_D * 2);
    unsigned short* buf1 = (unsigned short*)alloc((size_t)N * HID_D * 2);
    unsigned short* fx   = (unsigned short*)alloc((size_t)N * IN_D * 2);
    unsigned short* wc1  = (unsigned short*)alloc((size_t)3 * HID_D * IN_D * 2);
    unsigned short* wc2  = (unsigned short*)alloc((size_t)3 * HID_D * HID_D * 2);
    unsigned short* wpb  = (unsigned short*)alloc((size_t)OUT_D * HID_D * 2);
    int* cnt    = (int*)alloc((size_t)N * 4);
    unsigned short* elist = (unsigned short*)alloc((size_t)N * CAP * 2);  // 6.4 MB

    const int mc = (N + 15) / 16;         // 3125 chunks (16 rows)
    const int mg = 512;                   // 2 blocks/CU (512 thr), persistent
    const int pb = (N + 63) / 64;         // 782
    const int ab = (N + 3) / 4;           // 12500
    const int nfv = (N * IN_D) / 16;      // 400000
    const int fb = 2048;                  // 8 groups x 256 sub-blocks
    const int W = (E + 255) / 256;        // 2344 edges per sub-block window
    const int range = (N + 7) / 8;        // 6250 nodes per XCD group

    // cnt zeroed before the fill's atomics (separate dispatch: no race)
    hipMemsetAsync(cnt, 0, (size_t)N * 4, stream);
    // prep (weights+features->bf16) + XCD-partitioned edge fill
    k_prep_fill<<<fb, 256, 0, stream>>>(src, dst, cnt, elist, E, W, range,
                                        W1, F1, W2, F2, Wp,
                                        features, fx, nfv, wc1, wc2, wpb);

    // layer 1
    k_msg<<<mg, 512, 0, stream>>>(fx, wc1, buf1, N, mc);
    k_agg_ln<<<ab, 256, 0, stream>>>(buf1, elist, cnt, g1, b1, buf0, N);
    // layer 2
    k_msg<<<mg, 512, 0, stream>>>(buf0, wc2, buf1, N, mc);
    k_agg_ln<<<ab, 256, 0, stream>>>(buf1, elist, cnt, g2, b2, buf0, N);
    // projection + sigmoid
    k_proj<<<pb, 256, 0, stream>>>(buf0, wpb, bp, out, N);
}

// Round 13
// 224.888 us; speedup vs baseline: 1.2867x; 1.0353x over previous
//
#include <hip/hip_runtime.h>
#include <hip/hip_bf16.h>
#include <math.h>

#define IN_D 128
#define HID_D 128
#define OUT_D 64
#define CAP 64   // bucket capacity per node; Poisson(12) max over 50K nodes << 64

typedef __attribute__((ext_vector_type(8))) short bf16x8;
typedef __attribute__((ext_vector_type(4))) float f32x4;

__device__ __forceinline__ unsigned short f2bf(float f) {
    unsigned u = __float_as_uint(f);
    u += 0x7fffu + ((u >> 16) & 1u);   // RTNE
    return (unsigned short)(u >> 16);
}
__device__ __forceinline__ float bf2f(unsigned short h) {
    return __uint_as_float(((unsigned)h) << 16);
}

// ---- prep + XCD-partitioned edge fill ----
// Random 2B scatter from all 8 XCDs RMWs the same 64B lines in 8 incoherent
// L2s (47MB writeback for a 6.4MB elist). Group g = bid&7 (bid%8 XCD
// round-robin) keeps only edges with dst in its 1/8 node range: 8x coalesced
// re-read of src/dst (L3-absorbed) buys L2-local scatter; each XCD's elist
// slice (800KB) + cnt slice (25KB) stays resident, written back once.
__global__ __launch_bounds__(256) void k_prep_fill(
        const int* __restrict__ src_idx, const int* __restrict__ dst_idx,
        int* __restrict__ cnt, unsigned short* __restrict__ elist,
        int E, int W, int range,
        const float* __restrict__ W1, const float* __restrict__ F1,
        const float* __restrict__ W2, const float* __restrict__ F2,
        const float* __restrict__ Wp,
        const float* __restrict__ X, unsigned short* __restrict__ fx, int nfv,
        unsigned short* __restrict__ wc1, unsigned short* __restrict__ wc2,
        unsigned short* __restrict__ wpb) {
    int e = blockIdx.x * 256 + threadIdx.x;
    if (e < nfv) {   // nfv = N*IN_D/16 vector-chunks of 16 floats
        const float4* xp = (const float4*)X + (size_t)e * 4;
        float4 v0 = xp[0], v1 = xp[1], v2 = xp[2], v3 = xp[3];
        uint4 o0, o1;
        o0.x = (unsigned)f2bf(v0.x) | ((unsigned)f2bf(v0.y) << 16);
        o0.y = (unsigned)f2bf(v0.z) | ((unsigned)f2bf(v0.w) << 16);
        o0.z = (unsigned)f2bf(v1.x) | ((unsigned)f2bf(v1.y) << 16);
        o0.w = (unsigned)f2bf(v1.z) | ((unsigned)f2bf(v1.w) << 16);
        o1.x = (unsigned)f2bf(v2.x) | ((unsigned)f2bf(v2.y) << 16);
        o1.y = (unsigned)f2bf(v2.z) | ((unsigned)f2bf(v2.w) << 16);
        o1.z = (unsigned)f2bf(v3.x) | ((unsigned)f2bf(v3.y) << 16);
        o1.w = (unsigned)f2bf(v3.z) | ((unsigned)f2bf(v3.w) << 16);
        ((uint4*)fx)[(size_t)e * 2]     = o0;
        ((uint4*)fx)[(size_t)e * 2 + 1] = o1;
    }
    const int NW = HID_D * IN_D;          // 16384
    const int NC = 3 * NW;                // 49152
    const int NP = OUT_D * HID_D;         // 8192
    int i = e;
    if (i < NC) {
        wc1[i] = f2bf(i < NW ? W1[i] : F1[i - NW]);
    } else if (i < 2 * NC) {
        int j = i - NC;
        wc2[j] = f2bf(j < NW ? W2[j] : F2[j - NW]);
    } else if (i < 2 * NC + NP) {
        int j = i - 2 * NC;
        wpb[j] = f2bf(Wp[j]);
    }

    // ---- edge fill: group g scans edge window of sub-block, keeps its range
    const int g = blockIdx.x & 7;          // intended XCD id (bid%8 round-robin)
    const int sub = blockIdx.x >> 3;       // 0..255
    const int lo = g * range;
    const int base = sub * W;
    int end = base + W;
    if (end > E) end = E;
    for (int ed = base + threadIdx.x; ed < end; ed += 256) {
        int d = dst_idx[ed];
        int s = src_idx[ed];               // coalesced; ~88% of lines needed anyway
        if ((unsigned)(d - lo) < (unsigned)range) {
            int pos = atomicAdd(&cnt[d], 1);
            elist[(size_t)d * CAP + pos] = (unsigned short)s;
        }
    }
}

// ---- fused GEMM + FiLM: B-resident-ish, grid-stride over 16-row chunks.
// Measured floor for this shape: chunk-size, grid/occupancy, and B-residency
// restructures (rounds 9/12) all came back neutral-to-negative vs this config.
__global__ __launch_bounds__(256, 2) void k_msg(const unsigned short* __restrict__ X,
                                                const unsigned short* __restrict__ Wc,
                                                unsigned short* __restrict__ Msg,
                                                int n, int nchunks) {
    const int wave = threadIdx.x >> 6;
    const int lane = threadIdx.x & 63;
    const int lr = lane & 15;
    const int quad = lane >> 4;
    const int t0 = wave * 2;
    const int tidx[6] = {t0, t0 + 1, t0 + 8, t0 + 9, t0 + 16, t0 + 17};

    bf16x8 b[6][4];
    #pragma unroll
    for (int u = 0; u < 6; u++)
        #pragma unroll
        for (int s = 0; s < 4; s++)
            b[u][s] = *(const bf16x8*)(Wc + (size_t)(16 * tidx[u] + lr) * IN_D + quad * 8 + 32 * s);

    for (int c = blockIdx.x; c < nchunks; c += gridDim.x) {
        const int row0 = c << 4;   // 16 rows per chunk

        int r = row0 + lr;
        if (r > n - 1) r = n - 1;
        const unsigned short* xp = X + (size_t)r * IN_D + quad * 8;
        bf16x8 a[4];
        #pragma unroll
        for (int s = 0; s < 4; s++) a[s] = *(const bf16x8*)(xp + 32 * s);

        f32x4 acc[6];
        #pragma unroll
        for (int u = 0; u < 6; u++) acc[u] = (f32x4){0.f, 0.f, 0.f, 0.f};

        #pragma unroll
        for (int s = 0; s < 4; s++)
            #pragma unroll
            for (int u = 0; u < 6; u++)
                acc[u] = __builtin_amdgcn_mfma_f32_16x16x32_bf16(a[s], b[u][s], acc[u], 0, 0, 0);

        // FiLM: m=acc[0..1], gamma=acc[2..3], beta=acc[4..5]; identical slots.
        #pragma unroll
        for (int u = 0; u < 2; u++) {
            #pragma unroll
            for (int rr = 0; rr < 4; rr++) {
                int row = row0 + quad * 4 + rr;
                if (row < n) {
                    float v = acc[2 + u][rr] * acc[u][rr] + acc[4 + u][rr];
                    v = v > 0.f ? v : 0.f;
                    Msg[(size_t)row * HID_D + 16 * (t0 + u) + lr] = f2bf(v);
                }
            }
        }
    }
}

// ---- bucket aggregate + fused LayerNorm: uint4 gather, 16 lanes/row ----
// ALL __shfl calls under wave-uniform control flow (deg is wave-uniform);
// the remainder clamps the source lane to < deg so no shfl ever reads an
// exec-masked-off lane (ds_bpermute from an inactive source is undefined).
// Deeper in-flight batching (rounds 9/10) measured negative: addresses are
// loop-invariant in myidx so the compiler already pipelines this loop.
__global__ __launch_bounds__(256) void k_agg_ln(const unsigned short* __restrict__ Msg,
                                                const unsigned short* __restrict__ elist,
                                                const int* __restrict__ cnt,
                                                const float* __restrict__ gamma,
                                                const float* __restrict__ beta,
                                                unsigned short* __restrict__ Hout, int n) {
    int node = blockIdx.x * 4 + (threadIdx.x >> 6);
    int lane = threadIdx.x & 63;
    int g = lane >> 4;        // row-group 0..3
    int l16 = lane & 15;      // dims [l16*8, l16*8+8)
    if (node >= n) return;    // wave-uniform (node is per-wave)
    const unsigned short* seg = elist + (size_t)node * CAP;
    int deg = cnt[node];
    int myidx = seg[lane];    // one coalesced 128B load per wave
    float a0 = 0.f, a1 = 0.f, a2 = 0.f, a3 = 0.f;
    float a4 = 0.f, a5 = 0.f, a6 = 0.f, a7 = 0.f;

#define ACC8(v) { a0 += bf2f((unsigned short)((v).x & 0xffffu)); \
                  a1 += bf2f((unsigned short)((v).x >> 16));     \
                  a2 += bf2f((unsigned short)((v).y & 0xffffu)); \
                  a3 += bf2f((unsigned short)((v).y >> 16));     \
                  a4 += bf2f((unsigned short)((v).z & 0xffffu)); \
                  a5 += bf2f((unsigned short)((v).z >> 16));     \
                  a6 += bf2f((unsigned short)((v).w & 0xffffu)); \
                  a7 += bf2f((unsigned short)((v).w >> 16)); }

    int i = 0;
    for (; i + 8 <= deg; i += 8) {            // uniform condition
        int iA = __shfl(myidx, i + g);         // sources i..i+3 < deg, all lanes active
        int iB = __shfl(myidx, i + 4 + g);     // sources i+4..i+7 < deg
        uint4 vA = *(const uint4*)(Msg + (size_t)iA * HID_D + l16 * 8);
        uint4 vB = *(const uint4*)(Msg + (size_t)iB * HID_D + l16 * 8);
        ACC8(vA);
        ACC8(vB);
    }
    if (i + 4 <= deg) {                        // uniform
        int iA = __shfl(myidx, i + g);
        uint4 vA = *(const uint4*)(Msg + (size_t)iA * HID_D + l16 * 8);
        ACC8(vA);
        i += 4;
    }
    int rem = deg - i;                         // uniform, 0..3
    if (rem) {                                 // uniform
        int iA = __shfl(myidx, i + (g < rem ? g : 0));  // source < deg, shfl by all lanes
        if (g < rem) {                         // divergent load only, no shfl inside
            uint4 vA = *(const uint4*)(Msg + (size_t)iA * HID_D + l16 * 8);
            ACC8(vA);
        }
    }
#undef ACC8

    // combine the 4 row-groups: lanes with equal l16 end identical
    a0 += __shfl_xor(a0, 16); a1 += __shfl_xor(a1, 16);
    a2 += __shfl_xor(a2, 16); a3 += __shfl_xor(a3, 16);
    a4 += __shfl_xor(a4, 16); a5 += __shfl_xor(a5, 16);
    a6 += __shfl_xor(a6, 16); a7 += __shfl_xor(a7, 16);
    a0 += __shfl_xor(a0, 32); a1 += __shfl_xor(a1, 32);
    a2 += __shfl_xor(a2, 32); a3 += __shfl_xor(a3, 32);
    a4 += __shfl_xor(a4, 32); a5 += __shfl_xor(a5, 32);
    a6 += __shfl_xor(a6, 32); a7 += __shfl_xor(a7, 32);

    float s  = a0 + a1 + a2 + a3 + a4 + a5 + a6 + a7;
    float sq = a0 * a0 + a1 * a1 + a2 * a2 + a3 * a3
             + a4 * a4 + a5 * a5 + a6 * a6 + a7 * a7;
    #pragma unroll
    for (int d = 8; d; d >>= 1) {              // reduce across the 16 l16 lanes
        s += __shfl_xor(s, d);
        sq += __shfl_xor(sq, d);
    }
    float mu = s * (1.f / 128.f);
    float var = sq * (1.f / 128.f) - mu * mu;
    float rs = rsqrtf(var + 1e-5f);

    if (g == 0) {
        float4 g0 = ((const float4*)gamma)[l16 * 2];
        float4 g1 = ((const float4*)gamma)[l16 * 2 + 1];
        float4 b0 = ((const float4*)beta)[l16 * 2];
        float4 b1 = ((const float4*)beta)[l16 * 2 + 1];
        float y0 = (a0 - mu) * rs * g0.x + b0.x;
        float y1 = (a1 - mu) * rs * g0.y + b0.y;
        float y2 = (a2 - mu) * rs * g0.z + b0.z;
        float y3 = (a3 - mu) * rs * g0.w + b0.w;
        float y4 = (a4 - mu) * rs * g1.x + b1.x;
        float y5 = (a5 - mu) * rs * g1.y + b1.y;
        float y6 = (a6 - mu) * rs * g1.z + b1.z;
        float y7 = (a7 - mu) * rs * g1.w + b1.w;
        uint4 o;
        o.x = (unsigned)f2bf(y0) | ((unsigned)f2bf(y1) << 16);
        o.y = (unsigned)f2bf(y2) | ((unsigned)f2bf(y3) << 16);
        o.z = (unsigned)f2bf(y4) | ((unsigned)f2bf(y5) << 16);
        o.w = (unsigned)f2bf(y6) | ((unsigned)f2bf(y7) << 16);
        *(uint4*)(Hout + (size_t)node * HID_D + l16 * 8) = o;
    }
}

// ---- projection: out = sigmoid(h @ Wp^T + bp), 64 rows/block ----
// Kept separate: fusing into agg trips a compiler register-allocation
// pathology (VGPR pinned at 28 -> scratch spill, 112us; rounds 8/11).
__global__ __launch_bounds__(256) void k_proj(const unsigned short* __restrict__ H,
                                              const unsigned short* __restrict__ Wpb,
                                              const float* __restrict__ bp,
                                              float* __restrict__ out, int n) {
    const int row0 = blockIdx.x << 6;
    const int wave = threadIdx.x >> 6;
    const int lane = threadIdx.x & 63;
    const int lr = lane & 15;
    const int quad = lane >> 4;

    f32x4 acc[4];
    #pragma unroll
    for (int rt = 0; rt < 4; rt++) acc[rt] = (f32x4){0.f, 0.f, 0.f, 0.f};

    #pragma unroll
    for (int s = 0; s < 4; s++) {
        bf16x8 bv = *(const bf16x8*)(Wpb + (size_t)(16 * wave + lr) * HID_D + quad * 8 + 32 * s);
        #pragma unroll
        for (int rt = 0; rt < 4; rt++) {
            int r = row0 + rt * 16 + lr;
            if (r > n - 1) r = n - 1;
            bf16x8 av = *(const bf16x8*)(H + (size_t)r * HID_D + quad * 8 + 32 * s);
            acc[rt] = __builtin_amdgcn_mfma_f32_16x16x32_bf16(av, bv, acc[rt], 0, 0, 0);
        }
    }
    float bias = bp[16 * wave + lr];
    #pragma unroll
    for (int rt = 0; rt < 4; rt++) {
        #pragma unroll
        for (int r = 0; r < 4; r++) {
            int row = row0 + rt * 16 + quad * 4 + r;
            if (row < n) {
                float z = acc[rt][r] + bias;
                out[(size_t)row * OUT_D + 16 * wave + lr] = 1.f / (1.f + __expf(-z));
            }
        }
    }
}

extern "C" void kernel_launch(void* const* d_in, const int* in_sizes, int n_in,
                              void* d_out, int out_size, void* d_ws, size_t ws_size,
                              hipStream_t stream) {
    const float* features = (const float*)d_in[0];
    const int* src = (const int*)d_in[1];
    const int* dst = (const int*)d_in[2];
    const float* W1 = (const float*)d_in[3];
    const float* F1 = (const float*)d_in[4];
    const float* g1 = (const float*)d_in[5];
    const float* b1 = (const float*)d_in[6];
    const float* W2 = (const float*)d_in[7];
    const float* F2 = (const float*)d_in[8];
    const float* g2 = (const float*)d_in[9];
    const float* b2 = (const float*)d_in[10];
    const float* Wp = (const float*)d_in[11];
    const float* bp = (const float*)d_in[12];

    const int N = in_sizes[0] / IN_D;   // 50000
    const int E = in_sizes[1];          // 600000
    float* out = (float*)d_out;

    char* p = (char*)d_ws;
    auto alloc = [&](size_t b) -> char* {
        char* r = p;
        p += (b + 255) & ~(size_t)255;
        return r;
    };
    unsigned short* buf0 = (unsigned short*)alloc((size_t)N * HID_D * 2);
    unsigned short* buf1 = (unsigned short*)alloc((size_t)N * HID_D * 2);
    unsigned short* fx   = (unsigned short*)alloc((size_t)N * IN_D * 2);
    unsigned short* wc1  = (unsigned short*)alloc((size_t)3 * HID_D * IN_D * 2);
    unsigned short* wc2  = (unsigned short*)alloc((size_t)3 * HID_D * HID_D * 2);
    unsigned short* wpb  = (unsigned short*)alloc((size_t)OUT_D * HID_D * 2);
    int* cnt    = (int*)alloc((size_t)N * 4);
    unsigned short* elist = (unsigned short*)alloc((size_t)N * CAP * 2);  // 6.4 MB

    const int mc = (N + 15) / 16;         // 3125 chunks (16 rows)
    const int mg = 512;                   // 2 blocks/CU, persistent grid-stride
    const int pb = (N + 63) / 64;         // 782
    const int ab = (N + 3) / 4;           // 12500
    const int nfv = (N * IN_D) / 16;      // 400000
    const int fb = 2048;                  // 8 groups x 256 sub-blocks
    const int W = (E + 255) / 256;        // 2344 edges per sub-block window
    const int range = (N + 7) / 8;        // 6250 nodes per XCD group

    // cnt zeroed before the fill's atomics (separate dispatch: no race)
    hipMemsetAsync(cnt, 0, (size_t)N * 4, stream);
    // prep (weights+features->bf16) + XCD-partitioned edge fill
    k_prep_fill<<<fb, 256, 0, stream>>>(src, dst, cnt, elist, E, W, range,
                                        W1, F1, W2, F2, Wp,
                                        features, fx, nfv, wc1, wc2, wpb);

    // layer 1
    k_msg<<<mg, 256, 0, stream>>>(fx, wc1, buf1, N, mc);
    k_agg_ln<<<ab, 256, 0, stream>>>(buf1, elist, cnt, g1, b1, buf0, N);
    // layer 2
    k_msg<<<mg, 256, 0, stream>>>(buf0, wc2, buf1, N, mc);
    k_agg_ln<<<ab, 256, 0, stream>>>(buf1, elist, cnt, g2, b2, buf0, N);
    // projection + sigmoid
    k_proj<<<pb, 256, 0, stream>>>(buf0, wpb, bp, out, N);
}